// Round 1
// baseline (733.341 us; speedup 1.0000x reference)
//
#include <hip/hip_runtime.h>

namespace {

constexpr int CH = 32;
constexpr int HIMG = 192, WIMG = 192, NPIX = HIMG * WIMG;   // 36864
constexpr int WSZ = 16, PADS = 8;
constexpr int NHW = 12, NWIN = 144;
constexpr int MQ = 256, NKEY = 1024;
constexpr int NHEAD = 4, HDIM = 8;
constexpr float SCL = 0.35355339059327373f;   // 8^-0.5

__device__ __forceinline__ unsigned sortable(float d) {
  unsigned b = __float_as_uint(d);
  if ((b << 1) == 0u) b = 0u;                 // canonicalize -0 -> +0 (pad ties)
  return (b & 0x80000000u) ? ~b : (b | 0x80000000u);
}

// ---------------- proj_sample (1x1 conv, pixel-major) + normalized x ----------------
__global__ __launch_bounds__(256) void k_prep(const float* __restrict__ x,
                                              const float* __restrict__ Ws,
                                              const float* __restrict__ bs,
                                              float* __restrict__ y_px,
                                              float* __restrict__ xn) {
  __shared__ float w[64 * CH];
  __shared__ float b[64];
  int t = threadIdx.x;
  for (int i = t; i < 64 * CH; i += 256) w[i] = Ws[i];
  if (t < 64) b[t] = bs[t];
  __syncthreads();
  int pix = blockIdx.x * 256 + t;
  float xv[CH];
  float ss = 0.f;
#pragma unroll
  for (int c = 0; c < CH; ++c) { xv[c] = x[c * NPIX + pix]; ss += xv[c] * xv[c]; }
  float den = fmaxf(sqrtf(ss), 1e-12f);
#pragma unroll
  for (int c = 0; c < CH; ++c) xn[pix * CH + c] = xv[c] / den;
  for (int o = 0; o < 64; ++o) {
    float a = b[o];
#pragma unroll
    for (int c = 0; c < CH; ++c) a += w[o * CH + c] * xv[c];
    y_px[pix * 64 + o] = a;
  }
}

// ---------------- bilinear downsample 192->96 (antialias triangle) ----------------
__device__ __forceinline__ void down_w(int i, float w[4]) {
  w[0] = 0.125f; w[1] = 0.375f; w[2] = 0.375f; w[3] = 0.125f;
  if (i == 0)  { w[0] = 0.f;            w[1] = 0.75f / 1.75f; w[2] = 0.75f / 1.75f; w[3] = 0.25f / 1.75f; }
  if (i == 95) { w[0] = 0.25f / 1.75f;  w[1] = 0.75f / 1.75f; w[2] = 0.75f / 1.75f; w[3] = 0.f; }
}

__global__ __launch_bounds__(256) void k_down(const float* __restrict__ x,
                                              float* __restrict__ down) {
  int idx = blockIdx.x * 256 + threadIdx.x;
  if (idx >= CH * 96 * 96) return;
  int c = idx / (96 * 96);
  int r = (idx / 96) % 96;
  int q = idx % 96;
  float wr[4], wc[4];
  down_w(r, wr); down_w(q, wc);
  const float* xc = x + c * NPIX;
  float acc = 0.f;
#pragma unroll
  for (int a = 0; a < 4; ++a) {
    int rr = 2 * r - 1 + a;
    rr = rr < 0 ? 0 : (rr > HIMG - 1 ? HIMG - 1 : rr);
    float rowacc = 0.f;
#pragma unroll
    for (int bb = 0; bb < 4; ++bb) {
      int cc = 2 * q - 1 + bb;
      cc = cc < 0 ? 0 : (cc > WIMG - 1 ? WIMG - 1 : cc);
      rowacc += wc[bb] * xc[rr * WIMG + cc];
    }
    acc += wr[a] * rowacc;
  }
  down[idx] = acc;
}

// ---------------- bilinear upsample 96->192 + |x-up| channel-sum ----------------
__device__ __forceinline__ void up_taps(int i, int& j0, int& j1, float& w0, float& w1) {
  if (i == 0)        { j0 = 0;  j1 = 0;  w0 = 1.f;   w1 = 0.f;   return; }
  if (i == HIMG - 1) { j0 = 95; j1 = 95; w0 = 1.f;   w1 = 0.f;   return; }
  int tt = i >> 1;
  if ((i & 1) == 0)  { j0 = tt - 1; j1 = tt;     w0 = 0.25f; w1 = 0.75f; }
  else               { j0 = tt;     j1 = tt + 1; w0 = 0.75f; w1 = 0.25f; }
}

__global__ __launch_bounds__(256) void k_updiff(const float* __restrict__ x,
                                                const float* __restrict__ down,
                                                float* __restrict__ Xd) {
  int pix = blockIdx.x * 256 + threadIdx.x;
  int hh = pix / WIMG, wp = pix % WIMG;
  int r0, r1, c0, c1; float rw0, rw1, cw0, cw1;
  up_taps(hh, r0, r1, rw0, rw1);
  up_taps(wp, c0, c1, cw0, cw1);
  float s = 0.f;
  for (int c = 0; c < CH; ++c) {
    const float* d = down + c * 96 * 96;
    float up = rw0 * (cw0 * d[r0 * 96 + c0] + cw1 * d[r0 * 96 + c1]) +
               rw1 * (cw0 * d[r1 * 96 + c0] + cw1 * d[r1 * 96 + c1]);
    s += fabsf(x[c * NPIX + pix] - up);
  }
  Xd[pix] = s;
}

// ---------------- iterative proportional budget allocation ----------------
__global__ __launch_bounds__(256) void k_alloc(const float* __restrict__ Xd,
                                               int* __restrict__ Kall) {
  __shared__ float red[256];
  int win = blockIdx.x, t = threadIdx.x;
  int wh = win / NHW, ww = win % NHW;
  int pix = (wh * WSZ + (t >> 4)) * WIMG + ww * WSZ + (t & 15);
  float var = Xd[pix];
  float rest = 1.f;
  float budget = 65280.f;        // (TOPK-1)*M
  for (int it = 0; it < 4; ++it) {
    float vp = (rest < 1024.f) ? var : 0.f;
    red[t] = vp;
    __syncthreads();
    for (int s = 128; s > 0; s >>= 1) { if (t < s) red[t] += red[t + s]; __syncthreads(); }
    float sum = red[0];
    __syncthreads();
    float prop = vp / fmaxf(sum, 1e-12f);
    float nr = fminf(fmaxf(rest + rintf(prop * budget), 0.f), 1024.f);
    red[t] = nr - rest;
    __syncthreads();
    for (int s = 128; s > 0; s >>= 1) { if (t < s) red[t] += red[t + s]; __syncthreads(); }
    float dsum = red[0];
    __syncthreads();
    budget = fmaxf(budget - dsum, 0.f);
    rest = nr;
  }
  int K = (int)rest + 1;
  Kall[win * MQ + t] = K > 1024 ? 1024 : K;
}

// ---------------- q = l2norm(rope(Wg @ x_grp + bg)) ----------------
__global__ __launch_bounds__(256) void k_qn(const float* __restrict__ x,
                                            const float* __restrict__ Wg,
                                            const float* __restrict__ bg,
                                            float* __restrict__ qn) {
  __shared__ float w[CH * CH];
  __shared__ float b[CH];
  int t = threadIdx.x;
  for (int i = t; i < CH * CH; i += 256) w[i] = Wg[i];
  if (t < CH) b[t] = bg[t];
  __syncthreads();
  int win = blockIdx.x;
  int wh = win / NHW, ww = win % NHW;
  int m = t;
  int pix = (wh * WSZ + (m >> 4)) * WIMG + ww * WSZ + (m & 15);
  float o[CH];
#pragma unroll
  for (int oc = 0; oc < CH; ++oc) o[oc] = b[oc];
  for (int c = 0; c < CH; ++c) {
    float xv = x[c * NPIX + pix];
#pragma unroll
    for (int oc = 0; oc < CH; ++oc) o[oc] += w[oc * CH + c] * xv;
  }
  const float invf[4] = {1.f, 0.1f, 0.01f, 0.001f};
  float pos = (float)m;
#pragma unroll
  for (int h = 0; h < NHEAD; ++h) {
#pragma unroll
    for (int p = 0; p < 4; ++p) {
      float ang = pos * invf[p];
      float cs = cosf(ang), sn = sinf(ang);
      int i0 = h * HDIM + 2 * p;
      float a0 = o[i0], a1 = o[i0 + 1];
      o[i0]     = a0 * cs - a1 * sn;
      o[i0 + 1] = a1 * cs + a0 * sn;
    }
  }
#pragma unroll
  for (int h = 0; h < NHEAD; ++h) {
    float ss = 0.f;
#pragma unroll
    for (int d = 0; d < HDIM; ++d) { float v = o[h * HDIM + d]; ss += v * v; }
    float den = fmaxf(sqrtf(ss), 1e-12f);
#pragma unroll
    for (int d = 0; d < HDIM; ++d)
      qn[(win * MQ + m) * CH + h * HDIM + d] = o[h * HDIM + d] / den;
  }
}

// ---------------- graph: cosine-sim, stable top-K keep mask ----------------
__global__ __launch_bounds__(256) void k_graph(const float* __restrict__ xn,
                                               const int* __restrict__ Kall,
                                               unsigned* __restrict__ graph) {
  constexpr int QPB = 8;
  __shared__ float qloc[QPB][CH];
  __shared__ unsigned ubuf[QPB][NKEY];
  __shared__ unsigned hist[QPB][256];
  __shared__ unsigned prefq[QPB];
  __shared__ int remq[QPB];
  int win = blockIdx.x >> 5;
  int qg  = blockIdx.x & 31;
  int wh = win / NHW, ww = win % NHW;
  int t = threadIdx.x;
  {
    int qi = t >> 5, c = t & 31;
    int m = qg * QPB + qi;
    int pix = (wh * WSZ + (m >> 4)) * WIMG + ww * WSZ + (m & 15);
    qloc[qi][c] = xn[pix * CH + c];
  }
  __syncthreads();
  // D values for all 1024 keys (each thread owns key cc*256+t)
  for (int cc = 0; cc < 4; ++cc) {
    int j = cc * 256 + t;
    int k0 = j >> 5, k1 = j & 31;
    int py = wh * WSZ - PADS + k0, px = ww * WSZ - PADS + k1;
    bool inb = (py >= 0) && (py < HIMG) && (px >= 0) && (px < WIMG);
    float yv[CH];
    if (inb) {
      const float4* s4 = (const float4*)(xn + (py * WIMG + px) * CH);
#pragma unroll
      for (int r = 0; r < 8; ++r) {
        float4 v = s4[r];
        yv[4 * r] = v.x; yv[4 * r + 1] = v.y; yv[4 * r + 2] = v.z; yv[4 * r + 3] = v.w;
      }
    } else {
#pragma unroll
      for (int c = 0; c < CH; ++c) yv[c] = 0.f;
    }
#pragma unroll
    for (int q = 0; q < QPB; ++q) {
      float d = 0.f;
#pragma unroll
      for (int c = 0; c < CH; ++c) d += qloc[q][c] * yv[c];
      ubuf[q][j] = sortable(d);
    }
  }
  __syncthreads();
  // radix-select K-th largest; 32 lanes per query
  int g = t >> 5, l = t & 31;
  int g2 = g & 1;
  int m = qg * QPB + g;
  int K = Kall[win * MQ + m];
  unsigned pref = 0;
  int remK = K;
#pragma unroll
  for (int pass = 0; pass < 4; ++pass) {
#pragma unroll
    for (int bb = 0; bb < 8; ++bb) hist[g][l * 8 + bb] = 0u;
    __syncthreads();
    int shift = 24 - 8 * pass;
    for (int k = 0; k < 32; ++k) {
      unsigned uv = ubuf[g][k * 32 + l];
      unsigned hi = (pass == 0) ? 0u : (uv >> ((32 - 8 * pass) & 31));
      if (hi == pref) atomicAdd(&hist[g][(uv >> shift) & 255u], 1u);
    }
    __syncthreads();
    unsigned loc[8];
    unsigned su = 0;
#pragma unroll
    for (int bb = 7; bb >= 0; --bb) { su += hist[g][l * 8 + bb]; loc[bb] = su; }
    unsigned I = su;
#pragma unroll
    for (int off = 1; off < 32; off <<= 1) {
      unsigned v = __shfl_down(I, off, 32);
      if (l + off < 32) I += v;
    }
    unsigned E = I - su;   // totals of lanes > l (higher bins)
#pragma unroll
    for (int bb = 7; bb >= 0; --bb) {
      int sb  = (int)(loc[bb] + E);
      int sb1 = (int)((bb == 7 ? 0u : loc[bb + 1]) + E);
      if (sb >= remK && sb1 < remK) {
        prefq[g] = (pref << 8) | (unsigned)(l * 8 + bb);
        remq[g]  = remK - sb1;
      }
    }
    __syncthreads();
    pref = prefq[g];
    remK = remq[g];
    __syncthreads();
  }
  unsigned ustar = pref;
  int quota = remK;                 // how many equal-valued to keep (stable, ascending j)
  unsigned row = (unsigned)(win * MQ + m);
  int running = 0;
  for (int k = 0; k < 32; ++k) {
    unsigned uv = ubuf[g][k * 32 + l];
    bool eq = (uv == ustar);
    bool gt = (uv > ustar);
    unsigned long long bal = __ballot(eq);
    unsigned gm = (unsigned)(bal >> (g2 * 32));
    int before = running + __popc(gm & ((1u << l) - 1u));
    bool keep = gt || (eq && before < quota);
    running += __popc(gm);
    unsigned long long kb = __ballot(keep);
    unsigned gk = (unsigned)(kb >> (g2 * 32));
    if (l == 0) graph[row * 32 + k] = gk;
  }
}

// ---------------- attention: per (window, head), online softmax over kept keys ----------------
__global__ __launch_bounds__(256) void k_attn(const float* __restrict__ qn,
                                              const float* __restrict__ y_px,
                                              const unsigned* __restrict__ graph,
                                              float* __restrict__ att) {
  __shared__ float kn[HDIM][NKEY];   // 32KB
  __shared__ float fv[HDIM][NKEY];   // 32KB
  int win = blockIdx.x >> 2;
  int h = blockIdx.x & 3;
  int wh = win / NHW, ww = win % NHW;
  int t = threadIdx.x;
  const float invf[4] = {1.f, 0.1f, 0.01f, 0.001f};
#pragma unroll
  for (int r = 0; r < 4; ++r) {
    int j = r * 256 + t;
    int k0 = j >> 5, k1 = j & 31;
    int py = wh * WSZ - PADS + k0, px = ww * WSZ - PADS + k1;
    bool inb = (py >= 0) && (py < HIMG) && (px >= 0) && (px < WIMG);
    float kv[8], fw[8];
    if (inb) {
      const float* src = y_px + (py * WIMG + px) * 64 + h * HDIM;
      const float4* a4 = (const float4*)src;
      const float4* b4 = (const float4*)(src + 32);
      float4 a0 = a4[0], a1 = a4[1], b0 = b4[0], b1 = b4[1];
      kv[0]=a0.x; kv[1]=a0.y; kv[2]=a0.z; kv[3]=a0.w;
      kv[4]=a1.x; kv[5]=a1.y; kv[6]=a1.z; kv[7]=a1.w;
      fw[0]=b0.x; fw[1]=b0.y; fw[2]=b0.z; fw[3]=b0.w;
      fw[4]=b1.x; fw[5]=b1.y; fw[6]=b1.z; fw[7]=b1.w;
    } else {
#pragma unroll
      for (int d = 0; d < 8; ++d) { kv[d] = 0.f; fw[d] = 0.f; }
    }
    float ro[8];
    float posj = (float)j;
#pragma unroll
    for (int p = 0; p < 4; ++p) {
      float ang = posj * invf[p];
      float cs = cosf(ang), sn = sinf(ang);
      ro[2 * p]     = kv[2 * p] * cs - kv[2 * p + 1] * sn;
      ro[2 * p + 1] = kv[2 * p + 1] * cs + kv[2 * p] * sn;
    }
    float ss = 0.f;
#pragma unroll
    for (int d = 0; d < 8; ++d) ss += ro[d] * ro[d];
    float den = fmaxf(sqrtf(ss), 1e-12f);
#pragma unroll
    for (int d = 0; d < 8; ++d) { kn[d][j] = ro[d] / den; fv[d][j] = fw[d]; }
  }
  __syncthreads();
  int m = t;
  float q[8];
  const float* qp = qn + (win * MQ + m) * CH + h * HDIM;
#pragma unroll
  for (int d = 0; d < 8; ++d) q[d] = qp[d];
  const unsigned* gr = graph + (size_t)(win * MQ + m) * 32;
  float mrun = -1e30f, lrun = 0.f;
  float acc[8] = {0.f, 0.f, 0.f, 0.f, 0.f, 0.f, 0.f, 0.f};
  for (int wd = 0; wd < 32; ++wd) {
    unsigned bits = gr[wd];
    while (bits) {
      int bb = __ffs(bits) - 1;
      bits &= bits - 1;
      int j = wd * 32 + bb;
      float s = 0.f;
#pragma unroll
      for (int d = 0; d < 8; ++d) s += q[d] * kn[d][j];
      s *= SCL;
      if (s <= mrun) {
        float p = __expf(s - mrun);
        lrun += p;
#pragma unroll
        for (int d = 0; d < 8; ++d) acc[d] += p * fv[d][j];
      } else {
        float corr = __expf(mrun - s);
        lrun = lrun * corr + 1.f;
#pragma unroll
        for (int d = 0; d < 8; ++d) acc[d] = acc[d] * corr + fv[d][j];
        mrun = s;
      }
    }
  }
  float invl = 1.f / lrun;
  float* op = att + (size_t)(win * MQ + m) * CH + h * HDIM;
#pragma unroll
  for (int d = 0; d < 8; ++d) op[d] = acc[d] * invl;
}

// ---------------- out @ Wp^T + bp -> image layout ----------------
__global__ __launch_bounds__(256) void k_img(const float* __restrict__ att,
                                             const float* __restrict__ Wp,
                                             const float* __restrict__ bp,
                                             float* __restrict__ img) {
  __shared__ float w[CH * CH];
  __shared__ float b[CH];
  int t = threadIdx.x;
  for (int i = t; i < CH * CH; i += 256) w[i] = Wp[i];
  if (t < CH) b[t] = bp[t];
  __syncthreads();
  int gid = blockIdx.x * 256 + t;
  int win = gid >> 8, m = gid & 255;
  int wh = win / NHW, ww = win % NHW;
  int pix = (wh * WSZ + (m >> 4)) * WIMG + ww * WSZ + (m & 15);
  float a[CH];
#pragma unroll
  for (int c = 0; c < CH; ++c) a[c] = att[(size_t)gid * CH + c];
  for (int oc = 0; oc < CH; ++oc) {
    float acc = b[oc];
#pragma unroll
    for (int c = 0; c < CH; ++c) acc += w[oc * CH + c] * a[c];
    img[oc * NPIX + pix] = acc;
  }
}

// ---------------- 3x3 conv + channel LayerNorm + residual ----------------
__global__ __launch_bounds__(256) void k_convln(const float* __restrict__ img,
                                                const float* __restrict__ Wc,
                                                const float* __restrict__ bc,
                                                const float* __restrict__ gamma,
                                                const float* __restrict__ beta,
                                                float* __restrict__ out) {
  __shared__ float tile[CH][18][18];   // 41.5KB
  int t = threadIdx.x;
  int by = (blockIdx.x / 12) * 16, bx = (blockIdx.x % 12) * 16;
  for (int i = t; i < CH * 18 * 18; i += 256) {
    int c = i / 324; int rr = (i % 324) / 18; int cl = i % 18;
    int gy = by + rr - 1, gx = bx + cl - 1;
    tile[c][rr][cl] = (gy >= 0 && gy < HIMG && gx >= 0 && gx < WIMG)
                          ? img[c * NPIX + gy * WIMG + gx] : 0.f;
  }
  __syncthreads();
  int ty = t >> 4, tx = t & 15;
  float o[CH];
#pragma unroll
  for (int oc = 0; oc < CH; ++oc) o[oc] = bc[oc];
  for (int ic = 0; ic < CH; ++ic) {
#pragma unroll
    for (int dy = 0; dy < 3; ++dy) {
#pragma unroll
      for (int dx = 0; dx < 3; ++dx) {
        float xv = tile[ic][ty + dy][tx + dx];
#pragma unroll
        for (int oc = 0; oc < CH; ++oc)
          o[oc] += Wc[oc * 288 + ic * 9 + dy * 3 + dx] * xv;
      }
    }
  }
  float mu = 0.f;
#pragma unroll
  for (int oc = 0; oc < CH; ++oc) mu += o[oc];
  mu *= (1.f / 32.f);
  float var = 0.f;
#pragma unroll
  for (int oc = 0; oc < CH; ++oc) { float dd = o[oc] - mu; var += dd * dd; }
  var *= (1.f / 32.f);
  float inv = 1.f / sqrtf(var + 1e-5f);
  int pix = (by + ty) * WIMG + bx + tx;
#pragma unroll
  for (int oc = 0; oc < CH; ++oc)
    out[oc * NPIX + pix] = tile[oc][ty + 1][tx + 1] + (o[oc] - mu) * inv * gamma[oc] + beta[oc];
}

}  // namespace

extern "C" void kernel_launch(void* const* d_in, const int* in_sizes, int n_in,
                              void* d_out, int out_size, void* d_ws, size_t ws_size,
                              hipStream_t stream) {
  const float* x     = (const float*)d_in[0];
  const float* Wg    = (const float*)d_in[1];
  const float* bg    = (const float*)d_in[2];
  const float* Ws    = (const float*)d_in[3];
  const float* bs    = (const float*)d_in[4];
  const float* Wp    = (const float*)d_in[5];
  const float* bp    = (const float*)d_in[6];
  const float* Wc    = (const float*)d_in[7];
  const float* bc    = (const float*)d_in[8];
  const float* gamma = (const float*)d_in[9];
  const float* beta  = (const float*)d_in[10];
  float* out = (float*)d_out;
  float* ws = (float*)d_ws;

  float* y_px = ws;                             // 2359296 floats
  float* xn   = y_px + 2359296;                 // 1179648
  float* down = xn + 1179648;                   // 294912
  float* Xd   = down + 294912;                  // 36864
  float* qn   = Xd + 36864;                     // 1179648
  float* att  = qn + 1179648;                   // 1179648
  float* img  = att + 1179648;                  // 1179648
  int* Kall   = (int*)(img + 1179648);          // 36864
  unsigned* graph = (unsigned*)(Kall + 36864);  // 1179648
  if (ws_size < (size_t)8626176 * 4) return;

  k_prep<<<NPIX / 256, 256, 0, stream>>>(x, Ws, bs, y_px, xn);
  k_down<<<(CH * 96 * 96) / 256, 256, 0, stream>>>(x, down);
  k_updiff<<<NPIX / 256, 256, 0, stream>>>(x, down, Xd);
  k_alloc<<<NWIN, 256, 0, stream>>>(Xd, Kall);
  k_qn<<<NWIN, 256, 0, stream>>>(x, Wg, bg, qn);
  k_graph<<<NWIN * 32, 256, 0, stream>>>(xn, Kall, graph);
  k_attn<<<NWIN * NHEAD, 256, 0, stream>>>(qn, y_px, graph, att);
  k_img<<<NPIX / 256, 256, 0, stream>>>(att, Wp, bp, img);
  k_convln<<<NWIN, 256, 0, stream>>>(img, Wc, bc, gamma, beta, out);
}